// Round 15
// baseline (753.898 us; speedup 1.0000x reference)
//
#include <hip/hip_runtime.h>
#include <hip/hip_bf16.h>
#include <float.h>

// Problem constants: B=4, S=2048, D=1024, C=16384, k=8
#define R_TOTAL 8192
#define D_DIM   1024
#define C_TOTAL 16384
#define KSEL    8
#define XN  ((size_t)R_TOTAL * D_DIM)   // 8,388,608
#define CBN ((size_t)C_TOTAL * D_DIM)   // 16,777,216
#define NSPLIT  8
#define SEGC    (C_TOTAL / NSPLIT)      // 2048 codes per segment (per block)
#define NCHUNK  (SEGC / 256)            // 8 chunks of 256 codes
#define NKT     (NCHUNK * 16)           // 128 K-tiles (BK=64) per block
#define NC_RES  16                      // candidates exact-rescored per row

typedef __attribute__((ext_vector_type(8)))  short short8v;   // 8 bf16
typedef __attribute__((ext_vector_type(16))) float f32x16;

__device__ __forceinline__ unsigned short f2bf(float f) {  // RNE f32->bf16
  unsigned u = __float_as_uint(f);
  u = (u + 0x7fffu + ((u >> 16) & 1u)) >> 16;
  return (unsigned short)u;
}

__device__ __forceinline__ void gload_lds16(const void* g, void* l) {
  __builtin_amdgcn_global_load_lds((const __attribute__((address_space(1))) void*)g,
                                   (__attribute__((address_space(3))) void*)l, 16, 0, 0);
}

// ---------------------------------------------------------------------------
// Kernel 0: fused f32->bf16 conversion (X and CB) + c2 for CB rows.
// One wave per row. (r11/r14, passed; at HBM floor ~145MB)
// ---------------------------------------------------------------------------
__global__ __launch_bounds__(256)
void cvt_c2_kernel(const float* __restrict__ X, const float* __restrict__ CB,
                   unsigned short* __restrict__ Xb, unsigned short* __restrict__ CBb,
                   float* __restrict__ c2g) {
  const int row  = blockIdx.x * 4 + (threadIdx.x >> 6);
  const int lane = threadIdx.x & 63;
  const bool isCB = row >= R_TOTAL;
  const int rl = isCB ? row - R_TOTAL : row;
  const float* src = (isCB ? CB : X) + (size_t)rl * D_DIM;
  unsigned short* dst = (isCB ? CBb : Xb) + (size_t)rl * D_DIM;

  float ss = 0.f;
  #pragma unroll
  for (int i = 0; i < 4; ++i) {
    const float4 v = *(const float4*)(src + i * 256 + lane * 4);
    if (isCB) ss += v.x * v.x + v.y * v.y + v.z * v.z + v.w * v.w;
    ushort4 o;
    o.x = f2bf(v.x); o.y = f2bf(v.y); o.z = f2bf(v.z); o.w = f2bf(v.w);
    *(ushort4*)(dst + i * 256 + lane * 4) = o;
  }
  if (isCB) {
    #pragma unroll
    for (int off = 32; off >= 1; off >>= 1) ss += __shfl_xor(ss, off, 64);
    if (lane == 0) c2g[rl] = ss;
  }
}

// ---------------------------------------------------------------------------
// Kernel 1: bf16 MFMA GEMM (S^T: 256 codes x 256 xrows tile) with fused
// per-xrow approximate top-8 per 2048-code segment.
// MEASURED-OPTIMUM r6 kernel (417.9/418.0/417.9us reproduced 3x): E/O
// one-phase-ahead fragment pipeline, 4 barriers/tile, vmcnt(0)@p3.
// Sync-variant map (all measured): 2bar=430, 2bar+ahead=438, 1bar=453,
// 8phase-2bar=457, THIS (4bar+ahead)=418. VERBATIM - do not touch.
// ---------------------------------------------------------------------------
__global__ __launch_bounds__(512, 2)
void gemm_topk_kernel(const unsigned short* __restrict__ Xb,
                      const unsigned short* __restrict__ CBb,
                      const float* __restrict__ c2g,
                      float* __restrict__ pval, int* __restrict__ pid) {
  extern __shared__ char smem[];
  float* c2s = (float*)(smem + 131072);

  const int t   = threadIdx.x;
  const int wid = t >> 6, l = t & 63;
  const int wr  = wid >> 2;          // 0..1: code half (128 rows)
  const int wc  = wid & 3;           // 0..3: xrow quarter (64 cols)
  const int l31 = l & 31, hi = l >> 5;

  const int xt    = blockIdx.x & 31;        // 32 xrow tiles
  const int seg   = blockIdx.x >> 5;        // 8 segments
  const int xbase = xt * 256;
  const int cb0   = seg * SEGC;

  // preload segment c2 into LDS (512 thr x float4 = 2048 f32)
  *(float4*)&c2s[t * 4] = *(const float4*)(c2g + cb0 + t * 4);

  // staging: issue i covers rows i*64+(t>>3); 16B col chunk (t&7), swizzled src
  const int srow = t >> 3;
  const int sswz = (((t & 7) * 16) ^ ((srow & 7) << 4)) >> 1;  // elem offset
  const int fswz = (l & 7) << 4;                                // read swizzle

  f32x16 acc[4][2];
  float tv[2][KSEL]; int ti[2][KSEL];
  #pragma unroll
  for (int fm = 0; fm < 4; ++fm)
    #pragma unroll
    for (int fn = 0; fn < 2; ++fn)
      #pragma unroll
      for (int r = 0; r < 16; ++r) acc[fm][fn][r] = 0.f;
  #pragma unroll
  for (int fn = 0; fn < 2; ++fn)
    #pragma unroll
    for (int q = 0; q < KSEL; ++q) { tv[fn][q] = -FLT_MAX; ti[fn][q] = 0; }

  auto STAGE_A = [&](int g) {   // 4 loads: codes half-tiles of K-tile g
    const int kbase = (g & 15) * 64;
    const int arow0 = cb0 + (g >> 4) * 256;
    char* As = smem + (g & 1) * 32768;
    #pragma unroll
    for (int i = 0; i < 4; ++i)
      gload_lds16(CBb + (size_t)(arow0 + i * 64 + srow) * D_DIM + kbase + sswz,
                  As + (i * 512 + t) * 16);
  };
  auto STAGE_X = [&](int g) {   // 4 loads: xrow half-tiles of K-tile g
    const int kbase = (g & 15) * 64;
    char* Xs = smem + 65536 + (g & 1) * 32768;
    #pragma unroll
    for (int i = 0; i < 4; ++i)
      gload_lds16(Xb + (size_t)(xbase + i * 64 + srow) * D_DIM + kbase + sswz,
                  Xs + (i * 512 + t) * 16);
  };

  // two named fragment sets (static indexing only - rule 20)
  short8v avE[4], bvE[2], avO[4], bvO[2];

#define READ_FRAGS(AV, BV, ABUF, XBUF, P)                                       \
  {                                                                             \
    const int kb_ = ((P) * 32 + hi * 16) ^ fswz;                                \
    _Pragma("unroll")                                                           \
    for (int fm_ = 0; fm_ < 4; ++fm_)                                           \
      AV[fm_] = *(const short8v*)((ABUF) +                                      \
                    (wr * 128 + fm_ * 32 + l31) * 128 + kb_);                   \
    _Pragma("unroll")                                                           \
    for (int fn_ = 0; fn_ < 2; ++fn_)                                           \
      BV[fn_] = *(const short8v*)((XBUF) +                                      \
                    (wc * 64 + fn_ * 32 + l31) * 128 + kb_);                    \
  }

#define MFMA8(AV, BV)                                                           \
  {                                                                             \
    __builtin_amdgcn_s_setprio(1);                                              \
    _Pragma("unroll")                                                           \
    for (int fm_ = 0; fm_ < 4; ++fm_)                                           \
      _Pragma("unroll")                                                         \
      for (int fn_ = 0; fn_ < 2; ++fn_)                                         \
        acc[fm_][fn_] = __builtin_amdgcn_mfma_f32_32x32x16_bf16(                \
            AV[fm_], BV[fn_], acc[fm_][fn_], 0, 0, 0);                          \
    __builtin_amdgcn_s_setprio(0);                                              \
    __builtin_amdgcn_sched_barrier(0);                                          \
  }

  // ---- prologue: stage tile 0, drain, pre-read ks0 frags ----
  STAGE_A(0); STAGE_X(0);
  asm volatile("s_waitcnt vmcnt(0) lgkmcnt(0)" ::: "memory");
  __builtin_amdgcn_s_barrier();
  __builtin_amdgcn_sched_barrier(0);
  READ_FRAGS(avE, bvE, (const char*)smem, (const char*)smem + 65536, 0);

  for (int g = 0; g < NKT; ++g) {
    const char* As  = smem + (g & 1) * 32768;
    const char* Xs  = smem + 65536 + (g & 1) * 32768;
    const char* Asn = smem + ((g + 1) & 1) * 32768;
    const char* Xsn = smem + 65536 + ((g + 1) & 1) * 32768;
    const bool more = (g + 1 < NKT);

    // --- p0: consume E(ks0), issue O(ks1), stage A(g+1) ---
    READ_FRAGS(avO, bvO, As, Xs, 1);
    if (more) STAGE_A(g + 1);
    __builtin_amdgcn_s_barrier();
    MFMA8(avE, bvE);

    // --- p1: consume O(ks1), issue E(ks2), stage X(g+1) ---
    READ_FRAGS(avE, bvE, As, Xs, 2);
    if (more) STAGE_X(g + 1);
    __builtin_amdgcn_s_barrier();
    MFMA8(avO, bvO);

    // --- p2: consume E(ks2), issue O(ks3) ---
    READ_FRAGS(avO, bvO, As, Xs, 3);
    __builtin_amdgcn_s_barrier();
    MFMA8(avE, bvE);

    // --- p3: consume O(ks3), pre-read E(ks0 of g+1) from other buffer ---
    asm volatile("s_waitcnt vmcnt(0)" ::: "memory");  // stage g+1: 2-3 phases old
    __builtin_amdgcn_s_barrier();                      // ALL waves' stages landed
    __builtin_amdgcn_sched_barrier(0);
    if (more) READ_FRAGS(avE, bvE, Asn, Xsn, 0);
    MFMA8(avO, bvO);

    if ((g & 15) == 15) {
      // -------- selection epilogue for chunk ch (registers + c2s only) -----
      const int ch = g >> 4;
      #pragma unroll
      for (int fm = 0; fm < 4; ++fm) {
        const int rloc = ch * 256 + wr * 128 + fm * 32 + hi * 4;
        const int idb  = cb0 + ch * 256 + wr * 128 + fm * 32 + hi * 4;
        #pragma unroll
        for (int q = 0; q < 4; ++q) {
          const float4 cq = *(const float4*)&c2s[rloc + q * 8];
          #pragma unroll
          for (int fn = 0; fn < 2; ++fn) {
            #pragma unroll
            for (int r = 0; r < 4; ++r) {
              const float c2v = (r == 0) ? cq.x : (r == 1) ? cq.y : (r == 2) ? cq.z : cq.w;
              const float s = 2.f * acc[fm][fn][q * 4 + r] - c2v;
              if (s > tv[fn][KSEL - 1]) {      // strict >: ids scanned ascending
                float cv = s; int ci = idb + q * 8 + r;
                #pragma unroll
                for (int q2 = 0; q2 < KSEL; ++q2) {
                  if (cv > tv[fn][q2]) {
                    const float t0 = tv[fn][q2]; tv[fn][q2] = cv; cv = t0;
                    const int   t1 = ti[fn][q2]; ti[fn][q2] = ci; ci = t1;
                  }
                }
              }
            }
          }
        }
      }
      #pragma unroll
      for (int fm = 0; fm < 4; ++fm)
        #pragma unroll
        for (int fn = 0; fn < 2; ++fn)
          #pragma unroll
          for (int r = 0; r < 16; ++r) acc[fm][fn][r] = 0.f;
    }
  }

#undef READ_FRAGS
#undef MFMA8

  // -------- merge 4 lane-lists per xrow, write per-segment top-8 --------
  asm volatile("s_waitcnt vmcnt(0) lgkmcnt(0)" ::: "memory");
  __builtin_amdgcn_s_barrier();
  float* mv = (float*)smem;            // [256 xrows][4 lists][8] = 32KB
  int*   mi = (int*)(smem + 32768);
  #pragma unroll
  for (int fn = 0; fn < 2; ++fn) {
    const int xrL = wc * 64 + fn * 32 + l31;
    const int li  = wr * 2 + hi;
    #pragma unroll
    for (int q = 0; q < KSEL; ++q) {
      mv[xrL * 32 + li * 8 + q] = tv[fn][q];
      mi[xrL * 32 + li * 8 + q] = ti[fn][q];
    }
  }
  __syncthreads();
  if (t < 256) {
    float bvv[KSEL]; int bii[KSEL];
    #pragma unroll
    for (int q = 0; q < KSEL; ++q) { bvv[q] = -FLT_MAX; bii[q] = 0x7fffffff; }
    for (int c = 0; c < 32; ++c) {
      float cv = mv[t * 32 + c]; int ci = mi[t * 32 + c];
      if (cv > bvv[KSEL - 1] || (cv == bvv[KSEL - 1] && ci < bii[KSEL - 1])) {
        #pragma unroll
        for (int q = 0; q < KSEL; ++q) {
          if (cv > bvv[q] || (cv == bvv[q] && ci < bii[q])) {
            const float t0 = bvv[q]; bvv[q] = cv; cv = t0;
            const int   t1 = bii[q]; bii[q] = ci; ci = t1;
          }
        }
      }
    }
    const size_t base = ((size_t)(xbase + t) * NSPLIT + seg) * KSEL;
    #pragma unroll
    for (int q = 0; q < KSEL; ++q) { pval[base + q] = bvv[q]; pid[base + q] = bii[q]; }
  }
}

// ---------------------------------------------------------------------------
// Kernel 2: per row: merge 64 approx candidates -> top-16, exact f32 rescore
// of those 16, final top-8 (ties: lower id), gather + average.
// ROUND-15: the 16 candidate rows are staged into LDS during the dot phase
// (they're being read anyway); the final 8-row average is served from LDS
// instead of re-reading global CB (-262MB traffic, bit-identical output:
// same f32 values, same summation order as the 3x-passing kernel).
// LDS 68.3KB -> 2 blocks/CU (gather is L3/HBM-bound; wide loads keep BW).
// ---------------------------------------------------------------------------
__global__ __launch_bounds__(256)
void rescore_kernel(const float* __restrict__ X, const float* __restrict__ CB,
                    const float* __restrict__ c2g,
                    const float* __restrict__ pval, const int* __restrict__ pid,
                    float* __restrict__ out, float* __restrict__ out_ids) {
  const int row = blockIdx.x;
  const int t = threadIdx.x;
  __shared__ float xs[D_DIM];
  __shared__ float cs[NC_RES][D_DIM];   // 64KB: candidate rows, reused by gather
  __shared__ int   scid[NC_RES];
  __shared__ float sv[NC_RES];
  __shared__ int   topid[KSEL];
  __shared__ int   cpos[KSEL];

  *(float4*)&xs[t * 4] = *(const float4*)(X + (size_t)row * D_DIM + t * 4);

  const int ncand = NSPLIT * KSEL;          // 64

  if (t < 64) {   // wave 0: merge candidates by approx score -> top-NC ids
    float v   = pval[(size_t)row * ncand + t];
    int   idv = pid [(size_t)row * ncand + t];
    for (int it = 0; it < NC_RES; ++it) {
      float bv = v; int bid = idv;
      #pragma unroll
      for (int off = 32; off >= 1; off >>= 1) {
        float ov = __shfl_xor(bv, off, 64);
        int   oi = __shfl_xor(bid, off, 64);
        if (ov > bv || (ov == bv && oi < bid)) { bv = ov; bid = oi; }
      }
      if (t == 0) scid[it] = bid;
      if (idv == bid) v = -FLT_MAX;   // remove winner (ids unique)
    }
  }
  __syncthreads();

  const int w = t >> 6, ln = t & 63;
  for (int c = w; c < NC_RES; c += 4) {
    const int id = scid[c];
    const float* cr = CB + (size_t)id * D_DIM;
    float s = 0.f;
    #pragma unroll
    for (int i = 0; i < 4; ++i) {
      const float4 cv = *(const float4*)(cr + ln * 4 + i * 256);
      *(float4*)&cs[c][ln * 4 + i * 256] = cv;     // stage for the gather
      const float4 xv = *(const float4*)&xs[ln * 4 + i * 256];
      s += cv.x * xv.x + cv.y * xv.y + cv.z * xv.z + cv.w * xv.w;
    }
    #pragma unroll
    for (int off = 32; off >= 1; off >>= 1) s += __shfl_xor(s, off, 64);
    if (ln == 0) sv[c] = 2.f * s - c2g[id];
  }
  __syncthreads();

  if (t == 0) {
    float bv[KSEL]; int bi[KSEL];
    #pragma unroll
    for (int q = 0; q < KSEL; ++q) { bv[q] = -FLT_MAX; bi[q] = 0x7fffffff; }
    for (int c = 0; c < NC_RES; ++c) {
      float cv = sv[c]; int ci = scid[c];
      #pragma unroll
      for (int q = 0; q < KSEL; ++q) {
        if (cv > bv[q] || (cv == bv[q] && ci < bi[q])) {
          const float t0 = bv[q]; bv[q] = cv; cv = t0;
          const int   t1 = bi[q]; bi[q] = ci; ci = t1;
        }
      }
    }
    #pragma unroll
    for (int q = 0; q < KSEL; ++q) {
      topid[q] = bi[q];
      out_ids[(size_t)row * KSEL + q] = (float)bi[q];
    }
  }
  __syncthreads();

  if (t < KSEL) {   // map each winner id to its candidate slot (ids unique)
    const int my = topid[t];
    int p = 0;
    for (int c = 0; c < NC_RES; ++c) if (scid[c] == my) p = c;
    cpos[t] = p;
  }
  __syncthreads();

  float4 a = {0.f, 0.f, 0.f, 0.f};
  #pragma unroll
  for (int q = 0; q < KSEL; ++q) {   // same order, same f32 bits as before
    const float4 cv = *(const float4*)&cs[cpos[q]][t * 4];
    a.x += cv.x; a.y += cv.y; a.z += cv.z; a.w += cv.w;
  }
  a.x *= 0.125f; a.y *= 0.125f; a.z *= 0.125f; a.w *= 0.125f;
  *(float4*)(out + (size_t)row * D_DIM + t * 4) = a;
}

// ---------------------------------------------------------------------------
extern "C" void kernel_launch(void* const* d_in, const int* in_sizes, int n_in,
                              void* d_out, int out_size, void* d_ws, size_t ws_size,
                              hipStream_t stream) {
  const float* X  = (const float*)d_in[0];
  const float* CB = (const float*)d_in[1];
  // d_in[2] = kcodes, fixed at 8 (compiled in)

  float* out     = (float*)d_out;
  float* out_ids = out + XN;

  const size_t XbB  = XN * 2;        // 16 MB
  const size_t CBbB = CBN * 2;       // 32 MB
  const size_t c2B  = C_TOTAL * 4;   // 64 KB
  const size_t pvB  = (size_t)R_TOTAL * NSPLIT * KSEL * 4;  // 2 MB

  char* p = (char*)d_ws;
  unsigned short* Xb;
  unsigned short* CBb;
  if (ws_size >= XbB + CBbB + c2B + 2 * pvB) {
    Xb  = (unsigned short*)p; p += XbB;
    CBb = (unsigned short*)p; p += CBbB;
  } else {
    // CB bf16 lives in d_out's outputs region (overwritten at the very end)
    CBb = (unsigned short*)d_out;
    Xb  = (unsigned short*)p; p += XbB;
  }
  float* c2   = (float*)p; p += c2B;
  float* pval = (float*)p; p += pvB;
  int*   pid  = (int*)p;

  hipLaunchKernelGGL(cvt_c2_kernel, dim3((R_TOTAL + C_TOTAL) / 4), dim3(256), 0, stream,
                     X, CB, Xb, CBb, c2);
  hipLaunchKernelGGL(gemm_topk_kernel, dim3(32 * NSPLIT), dim3(512), 136 * 1024, stream,
                     Xb, CBb, c2, pval, pid);
  hipLaunchKernelGGL(rescore_kernel, dim3(R_TOTAL), dim3(256), 0, stream,
                     X, CB, c2, pval, pid, out, out_ids);
}

// Round 16
// 541.611 us; speedup vs baseline: 1.3920x; 1.3920x over previous
//
#include <hip/hip_runtime.h>
#include <hip/hip_bf16.h>
#include <float.h>

// Problem constants: B=4, S=2048, D=1024, C=16384, k=8
#define R_TOTAL 8192
#define D_DIM   1024
#define C_TOTAL 16384
#define KSEL    8
#define XN  ((size_t)R_TOTAL * D_DIM)   // 8,388,608
#define CBN ((size_t)C_TOTAL * D_DIM)   // 16,777,216
#define NSPLIT  8
#define SEGC    (C_TOTAL / NSPLIT)      // 2048 codes per segment (per block)
#define NCHUNK  (SEGC / 256)            // 8 chunks of 256 codes
#define NKT     (NCHUNK * 16)           // 128 K-tiles (BK=64) per block
#define NC_RES  16                      // candidates exact-rescored per row

typedef __attribute__((ext_vector_type(8)))  short short8v;   // 8 bf16
typedef __attribute__((ext_vector_type(16))) float f32x16;

__device__ __forceinline__ unsigned short f2bf(float f) {  // RNE f32->bf16
  unsigned u = __float_as_uint(f);
  u = (u + 0x7fffu + ((u >> 16) & 1u)) >> 16;
  return (unsigned short)u;
}

__device__ __forceinline__ void gload_lds16(const void* g, void* l) {
  __builtin_amdgcn_global_load_lds((const __attribute__((address_space(1))) void*)g,
                                   (__attribute__((address_space(3))) void*)l, 16, 0, 0);
}

// ---------------------------------------------------------------------------
// Kernel 0: fused f32->bf16 conversion (X and CB) + c2 for CB rows.
// One wave per row. (r11/r14, passed; at HBM floor ~145MB)
// ---------------------------------------------------------------------------
__global__ __launch_bounds__(256)
void cvt_c2_kernel(const float* __restrict__ X, const float* __restrict__ CB,
                   unsigned short* __restrict__ Xb, unsigned short* __restrict__ CBb,
                   float* __restrict__ c2g) {
  const int row  = blockIdx.x * 4 + (threadIdx.x >> 6);
  const int lane = threadIdx.x & 63;
  const bool isCB = row >= R_TOTAL;
  const int rl = isCB ? row - R_TOTAL : row;
  const float* src = (isCB ? CB : X) + (size_t)rl * D_DIM;
  unsigned short* dst = (isCB ? CBb : Xb) + (size_t)rl * D_DIM;

  float ss = 0.f;
  #pragma unroll
  for (int i = 0; i < 4; ++i) {
    const float4 v = *(const float4*)(src + i * 256 + lane * 4);
    if (isCB) ss += v.x * v.x + v.y * v.y + v.z * v.z + v.w * v.w;
    ushort4 o;
    o.x = f2bf(v.x); o.y = f2bf(v.y); o.z = f2bf(v.z); o.w = f2bf(v.w);
    *(ushort4*)(dst + i * 256 + lane * 4) = o;
  }
  if (isCB) {
    #pragma unroll
    for (int off = 32; off >= 1; off >>= 1) ss += __shfl_xor(ss, off, 64);
    if (lane == 0) c2g[rl] = ss;
  }
}

// ---------------------------------------------------------------------------
// Kernel 1: bf16 MFMA GEMM (S^T: 256 codes x 256 xrows tile) with fused
// per-xrow approximate top-8 per 2048-code segment.
// MEASURED-OPTIMUM r6 kernel (417.9/418.0/417.9/418.4us reproduced 4x): E/O
// one-phase-ahead fragment pipeline, 4 barriers/tile, vmcnt(0)@p3.
// Sync-variant map (all measured): 2bar=430, 2bar+ahead=438, 1bar=453,
// 8phase-2bar=457, THIS (4bar+ahead)=418. VERBATIM - do not touch.
// Rescore-LDS-staging (r15): 68KB cache -> 2 blk/CU -> latency-bound, +210us.
// ---------------------------------------------------------------------------
__global__ __launch_bounds__(512, 2)
void gemm_topk_kernel(const unsigned short* __restrict__ Xb,
                      const unsigned short* __restrict__ CBb,
                      const float* __restrict__ c2g,
                      float* __restrict__ pval, int* __restrict__ pid) {
  extern __shared__ char smem[];
  float* c2s = (float*)(smem + 131072);

  const int t   = threadIdx.x;
  const int wid = t >> 6, l = t & 63;
  const int wr  = wid >> 2;          // 0..1: code half (128 rows)
  const int wc  = wid & 3;           // 0..3: xrow quarter (64 cols)
  const int l31 = l & 31, hi = l >> 5;

  const int xt    = blockIdx.x & 31;        // 32 xrow tiles
  const int seg   = blockIdx.x >> 5;        // 8 segments
  const int xbase = xt * 256;
  const int cb0   = seg * SEGC;

  // preload segment c2 into LDS (512 thr x float4 = 2048 f32)
  *(float4*)&c2s[t * 4] = *(const float4*)(c2g + cb0 + t * 4);

  // staging: issue i covers rows i*64+(t>>3); 16B col chunk (t&7), swizzled src
  const int srow = t >> 3;
  const int sswz = (((t & 7) * 16) ^ ((srow & 7) << 4)) >> 1;  // elem offset
  const int fswz = (l & 7) << 4;                                // read swizzle

  f32x16 acc[4][2];
  float tv[2][KSEL]; int ti[2][KSEL];
  #pragma unroll
  for (int fm = 0; fm < 4; ++fm)
    #pragma unroll
    for (int fn = 0; fn < 2; ++fn)
      #pragma unroll
      for (int r = 0; r < 16; ++r) acc[fm][fn][r] = 0.f;
  #pragma unroll
  for (int fn = 0; fn < 2; ++fn)
    #pragma unroll
    for (int q = 0; q < KSEL; ++q) { tv[fn][q] = -FLT_MAX; ti[fn][q] = 0; }

  auto STAGE_A = [&](int g) {   // 4 loads: codes half-tiles of K-tile g
    const int kbase = (g & 15) * 64;
    const int arow0 = cb0 + (g >> 4) * 256;
    char* As = smem + (g & 1) * 32768;
    #pragma unroll
    for (int i = 0; i < 4; ++i)
      gload_lds16(CBb + (size_t)(arow0 + i * 64 + srow) * D_DIM + kbase + sswz,
                  As + (i * 512 + t) * 16);
  };
  auto STAGE_X = [&](int g) {   // 4 loads: xrow half-tiles of K-tile g
    const int kbase = (g & 15) * 64;
    char* Xs = smem + 65536 + (g & 1) * 32768;
    #pragma unroll
    for (int i = 0; i < 4; ++i)
      gload_lds16(Xb + (size_t)(xbase + i * 64 + srow) * D_DIM + kbase + sswz,
                  Xs + (i * 512 + t) * 16);
  };

  // two named fragment sets (static indexing only - rule 20)
  short8v avE[4], bvE[2], avO[4], bvO[2];

#define READ_FRAGS(AV, BV, ABUF, XBUF, P)                                       \
  {                                                                             \
    const int kb_ = ((P) * 32 + hi * 16) ^ fswz;                                \
    _Pragma("unroll")                                                           \
    for (int fm_ = 0; fm_ < 4; ++fm_)                                           \
      AV[fm_] = *(const short8v*)((ABUF) +                                      \
                    (wr * 128 + fm_ * 32 + l31) * 128 + kb_);                   \
    _Pragma("unroll")                                                           \
    for (int fn_ = 0; fn_ < 2; ++fn_)                                           \
      BV[fn_] = *(const short8v*)((XBUF) +                                      \
                    (wc * 64 + fn_ * 32 + l31) * 128 + kb_);                    \
  }

#define MFMA8(AV, BV)                                                           \
  {                                                                             \
    __builtin_amdgcn_s_setprio(1);                                              \
    _Pragma("unroll")                                                           \
    for (int fm_ = 0; fm_ < 4; ++fm_)                                           \
      _Pragma("unroll")                                                         \
      for (int fn_ = 0; fn_ < 2; ++fn_)                                         \
        acc[fm_][fn_] = __builtin_amdgcn_mfma_f32_32x32x16_bf16(                \
            AV[fm_], BV[fn_], acc[fm_][fn_], 0, 0, 0);                          \
    __builtin_amdgcn_s_setprio(0);                                              \
    __builtin_amdgcn_sched_barrier(0);                                          \
  }

  // ---- prologue: stage tile 0, drain, pre-read ks0 frags ----
  STAGE_A(0); STAGE_X(0);
  asm volatile("s_waitcnt vmcnt(0) lgkmcnt(0)" ::: "memory");
  __builtin_amdgcn_s_barrier();
  __builtin_amdgcn_sched_barrier(0);
  READ_FRAGS(avE, bvE, (const char*)smem, (const char*)smem + 65536, 0);

  for (int g = 0; g < NKT; ++g) {
    const char* As  = smem + (g & 1) * 32768;
    const char* Xs  = smem + 65536 + (g & 1) * 32768;
    const char* Asn = smem + ((g + 1) & 1) * 32768;
    const char* Xsn = smem + 65536 + ((g + 1) & 1) * 32768;
    const bool more = (g + 1 < NKT);

    // --- p0: consume E(ks0), issue O(ks1), stage A(g+1) ---
    READ_FRAGS(avO, bvO, As, Xs, 1);
    if (more) STAGE_A(g + 1);
    __builtin_amdgcn_s_barrier();
    MFMA8(avE, bvE);

    // --- p1: consume O(ks1), issue E(ks2), stage X(g+1) ---
    READ_FRAGS(avE, bvE, As, Xs, 2);
    if (more) STAGE_X(g + 1);
    __builtin_amdgcn_s_barrier();
    MFMA8(avO, bvO);

    // --- p2: consume E(ks2), issue O(ks3) ---
    READ_FRAGS(avO, bvO, As, Xs, 3);
    __builtin_amdgcn_s_barrier();
    MFMA8(avE, bvE);

    // --- p3: consume O(ks3), pre-read E(ks0 of g+1) from other buffer ---
    asm volatile("s_waitcnt vmcnt(0)" ::: "memory");  // stage g+1: 2-3 phases old
    __builtin_amdgcn_s_barrier();                      // ALL waves' stages landed
    __builtin_amdgcn_sched_barrier(0);
    if (more) READ_FRAGS(avE, bvE, Asn, Xsn, 0);
    MFMA8(avO, bvO);

    if ((g & 15) == 15) {
      // -------- selection epilogue for chunk ch (registers + c2s only) -----
      const int ch = g >> 4;
      #pragma unroll
      for (int fm = 0; fm < 4; ++fm) {
        const int rloc = ch * 256 + wr * 128 + fm * 32 + hi * 4;
        const int idb  = cb0 + ch * 256 + wr * 128 + fm * 32 + hi * 4;
        #pragma unroll
        for (int q = 0; q < 4; ++q) {
          const float4 cq = *(const float4*)&c2s[rloc + q * 8];
          #pragma unroll
          for (int fn = 0; fn < 2; ++fn) {
            #pragma unroll
            for (int r = 0; r < 4; ++r) {
              const float c2v = (r == 0) ? cq.x : (r == 1) ? cq.y : (r == 2) ? cq.z : cq.w;
              const float s = 2.f * acc[fm][fn][q * 4 + r] - c2v;
              if (s > tv[fn][KSEL - 1]) {      // strict >: ids scanned ascending
                float cv = s; int ci = idb + q * 8 + r;
                #pragma unroll
                for (int q2 = 0; q2 < KSEL; ++q2) {
                  if (cv > tv[fn][q2]) {
                    const float t0 = tv[fn][q2]; tv[fn][q2] = cv; cv = t0;
                    const int   t1 = ti[fn][q2]; ti[fn][q2] = ci; ci = t1;
                  }
                }
              }
            }
          }
        }
      }
      #pragma unroll
      for (int fm = 0; fm < 4; ++fm)
        #pragma unroll
        for (int fn = 0; fn < 2; ++fn)
          #pragma unroll
          for (int r = 0; r < 16; ++r) acc[fm][fn][r] = 0.f;
    }
  }

#undef READ_FRAGS
#undef MFMA8

  // -------- merge 4 lane-lists per xrow, write per-segment top-8 --------
  asm volatile("s_waitcnt vmcnt(0) lgkmcnt(0)" ::: "memory");
  __builtin_amdgcn_s_barrier();
  float* mv = (float*)smem;            // [256 xrows][4 lists][8] = 32KB
  int*   mi = (int*)(smem + 32768);
  #pragma unroll
  for (int fn = 0; fn < 2; ++fn) {
    const int xrL = wc * 64 + fn * 32 + l31;
    const int li  = wr * 2 + hi;
    #pragma unroll
    for (int q = 0; q < KSEL; ++q) {
      mv[xrL * 32 + li * 8 + q] = tv[fn][q];
      mi[xrL * 32 + li * 8 + q] = ti[fn][q];
    }
  }
  __syncthreads();
  if (t < 256) {
    float bvv[KSEL]; int bii[KSEL];
    #pragma unroll
    for (int q = 0; q < KSEL; ++q) { bvv[q] = -FLT_MAX; bii[q] = 0x7fffffff; }
    for (int c = 0; c < 32; ++c) {
      float cv = mv[t * 32 + c]; int ci = mi[t * 32 + c];
      if (cv > bvv[KSEL - 1] || (cv == bvv[KSEL - 1] && ci < bii[KSEL - 1])) {
        #pragma unroll
        for (int q = 0; q < KSEL; ++q) {
          if (cv > bvv[q] || (cv == bvv[q] && ci < bii[q])) {
            const float t0 = bvv[q]; bvv[q] = cv; cv = t0;
            const int   t1 = bii[q]; bii[q] = ci; ci = t1;
          }
        }
      }
    }
    const size_t base = ((size_t)(xbase + t) * NSPLIT + seg) * KSEL;
    #pragma unroll
    for (int q = 0; q < KSEL; ++q) { pval[base + q] = bvv[q]; pid[base + q] = bii[q]; }
  }
}

// ---------------------------------------------------------------------------
// Kernel 2: per row: merge 64 approx candidates -> top-16, exact f32 rescore
// of those 16, final top-8 (ties: lower id), gather + average. (r11/r14,
// passed; ~100us. r15's LDS-staged variant measured +210us - keep global
// gather with high occupancy.)
// ---------------------------------------------------------------------------
__global__ __launch_bounds__(256)
void rescore_kernel(const float* __restrict__ X, const float* __restrict__ CB,
                    const float* __restrict__ c2g,
                    const float* __restrict__ pval, const int* __restrict__ pid,
                    float* __restrict__ out, float* __restrict__ out_ids) {
  const int row = blockIdx.x;
  const int t = threadIdx.x;
  __shared__ float xs[D_DIM];
  __shared__ int   scid[NC_RES];
  __shared__ float sv[NC_RES];
  __shared__ int   topid[KSEL];

  *(float4*)&xs[t * 4] = *(const float4*)(X + (size_t)row * D_DIM + t * 4);

  const int ncand = NSPLIT * KSEL;          // 64

  if (t < 64) {   // wave 0: merge candidates by approx score -> top-NC ids
    float v   = pval[(size_t)row * ncand + t];
    int   idv = pid [(size_t)row * ncand + t];
    for (int it = 0; it < NC_RES; ++it) {
      float bv = v; int bid = idv;
      #pragma unroll
      for (int off = 32; off >= 1; off >>= 1) {
        float ov = __shfl_xor(bv, off, 64);
        int   oi = __shfl_xor(bid, off, 64);
        if (ov > bv || (ov == bv && oi < bid)) { bv = ov; bid = oi; }
      }
      if (t == 0) scid[it] = bid;
      if (idv == bid) v = -FLT_MAX;   // remove winner (ids unique)
    }
  }
  __syncthreads();

  const int w = t >> 6, ln = t & 63;
  for (int c = w; c < NC_RES; c += 4) {
    const int id = scid[c];
    const float* cr = CB + (size_t)id * D_DIM;
    float s = 0.f;
    #pragma unroll
    for (int i = 0; i < 4; ++i) {
      const float4 cv = *(const float4*)(cr + ln * 4 + i * 256);
      const float4 xv = *(const float4*)&xs[ln * 4 + i * 256];
      s += cv.x * xv.x + cv.y * xv.y + cv.z * xv.z + cv.w * xv.w;
    }
    #pragma unroll
    for (int off = 32; off >= 1; off >>= 1) s += __shfl_xor(s, off, 64);
    if (ln == 0) sv[c] = 2.f * s - c2g[id];
  }
  __syncthreads();

  if (t == 0) {
    float bv[KSEL]; int bi[KSEL];
    #pragma unroll
    for (int q = 0; q < KSEL; ++q) { bv[q] = -FLT_MAX; bi[q] = 0x7fffffff; }
    for (int c = 0; c < NC_RES; ++c) {
      float cv = sv[c]; int ci = scid[c];
      #pragma unroll
      for (int q = 0; q < KSEL; ++q) {
        if (cv > bv[q] || (cv == bv[q] && ci < bi[q])) {
          const float t0 = bv[q]; bv[q] = cv; cv = t0;
          const int   t1 = bi[q]; bi[q] = ci; ci = t1;
        }
      }
    }
    #pragma unroll
    for (int q = 0; q < KSEL; ++q) {
      topid[q] = bi[q];
      out_ids[(size_t)row * KSEL + q] = (float)bi[q];
    }
  }
  __syncthreads();

  float4 a = {0.f, 0.f, 0.f, 0.f};
  #pragma unroll
  for (int q = 0; q < KSEL; ++q) {
    const float4 cv = *(const float4*)(CB + (size_t)topid[q] * D_DIM + t * 4);
    a.x += cv.x; a.y += cv.y; a.z += cv.z; a.w += cv.w;
  }
  a.x *= 0.125f; a.y *= 0.125f; a.z *= 0.125f; a.w *= 0.125f;
  *(float4*)(out + (size_t)row * D_DIM + t * 4) = a;
}

// ---------------------------------------------------------------------------
extern "C" void kernel_launch(void* const* d_in, const int* in_sizes, int n_in,
                              void* d_out, int out_size, void* d_ws, size_t ws_size,
                              hipStream_t stream) {
  const float* X  = (const float*)d_in[0];
  const float* CB = (const float*)d_in[1];
  // d_in[2] = kcodes, fixed at 8 (compiled in)

  float* out     = (float*)d_out;
  float* out_ids = out + XN;

  const size_t XbB  = XN * 2;        // 16 MB
  const size_t CBbB = CBN * 2;       // 32 MB
  const size_t c2B  = C_TOTAL * 4;   // 64 KB
  const size_t pvB  = (size_t)R_TOTAL * NSPLIT * KSEL * 4;  // 2 MB

  char* p = (char*)d_ws;
  unsigned short* Xb;
  unsigned short* CBb;
  if (ws_size >= XbB + CBbB + c2B + 2 * pvB) {
    Xb  = (unsigned short*)p; p += XbB;
    CBb = (unsigned short*)p; p += CBbB;
  } else {
    // CB bf16 lives in d_out's outputs region (overwritten at the very end)
    CBb = (unsigned short*)d_out;
    Xb  = (unsigned short*)p; p += XbB;
  }
  float* c2   = (float*)p; p += c2B;
  float* pval = (float*)p; p += pvB;
  int*   pid  = (int*)p;

  hipLaunchKernelGGL(cvt_c2_kernel, dim3((R_TOTAL + C_TOTAL) / 4), dim3(256), 0, stream,
                     X, CB, Xb, CBb, c2);
  hipLaunchKernelGGL(gemm_topk_kernel, dim3(32 * NSPLIT), dim3(512), 136 * 1024, stream,
                     Xb, CBb, c2, pval, pid);
  hipLaunchKernelGGL(rescore_kernel, dim3(R_TOTAL), dim3(256), 0, stream,
                     X, CB, c2, pval, pid, out, out_ids);
}

// Round 17
// 538.835 us; speedup vs baseline: 1.3991x; 1.0052x over previous
//
#include <hip/hip_runtime.h>
#include <hip/hip_bf16.h>
#include <float.h>

// Problem constants: B=4, S=2048, D=1024, C=16384, k=8
#define R_TOTAL 8192
#define D_DIM   1024
#define C_TOTAL 16384
#define KSEL    8
#define XN  ((size_t)R_TOTAL * D_DIM)   // 8,388,608
#define CBN ((size_t)C_TOTAL * D_DIM)   // 16,777,216
#define NSPLIT  8
#define SEGC    (C_TOTAL / NSPLIT)      // 2048 codes per segment (per block)
#define NCHUNK  (SEGC / 256)            // 8 chunks of 256 codes
#define NKT     (NCHUNK * 16)           // 128 K-tiles (BK=64) per block
#define NC_RES  16                      // candidates exact-rescored per row

typedef __attribute__((ext_vector_type(8)))  short short8v;   // 8 bf16
typedef __attribute__((ext_vector_type(16))) float f32x16;

__device__ __forceinline__ unsigned short f2bf(float f) {  // RNE f32->bf16
  unsigned u = __float_as_uint(f);
  u = (u + 0x7fffu + ((u >> 16) & 1u)) >> 16;
  return (unsigned short)u;
}

__device__ __forceinline__ void gload_lds16(const void* g, void* l) {
  __builtin_amdgcn_global_load_lds((const __attribute__((address_space(1))) void*)g,
                                   (__attribute__((address_space(3))) void*)l, 16, 0, 0);
}

// ---------------------------------------------------------------------------
// Kernel 0: fused f32->bf16 conversion (X and CB) + c2 for CB rows.
// One wave per row. (r11/r14/r16, passed; at HBM floor ~145MB)
// ---------------------------------------------------------------------------
__global__ __launch_bounds__(256)
void cvt_c2_kernel(const float* __restrict__ X, const float* __restrict__ CB,
                   unsigned short* __restrict__ Xb, unsigned short* __restrict__ CBb,
                   float* __restrict__ c2g) {
  const int row  = blockIdx.x * 4 + (threadIdx.x >> 6);
  const int lane = threadIdx.x & 63;
  const bool isCB = row >= R_TOTAL;
  const int rl = isCB ? row - R_TOTAL : row;
  const float* src = (isCB ? CB : X) + (size_t)rl * D_DIM;
  unsigned short* dst = (isCB ? CBb : Xb) + (size_t)rl * D_DIM;

  float ss = 0.f;
  #pragma unroll
  for (int i = 0; i < 4; ++i) {
    const float4 v = *(const float4*)(src + i * 256 + lane * 4);
    if (isCB) ss += v.x * v.x + v.y * v.y + v.z * v.z + v.w * v.w;
    ushort4 o;
    o.x = f2bf(v.x); o.y = f2bf(v.y); o.z = f2bf(v.z); o.w = f2bf(v.w);
    *(ushort4*)(dst + i * 256 + lane * 4) = o;
  }
  if (isCB) {
    #pragma unroll
    for (int off = 32; off >= 1; off >>= 1) ss += __shfl_xor(ss, off, 64);
    if (lane == 0) c2g[rl] = ss;
  }
}

// ---------------------------------------------------------------------------
// Kernel 1: bf16 MFMA GEMM (S^T: 256 codes x 256 xrows tile) with fused
// per-xrow approximate top-8 per 2048-code segment.
// r6 optimum (418us x5) with ONE delta: BOTH stage issues (A and X of
// tile g+1) moved to p0, so the p3 vmcnt(0) waits on loads ~3 phases
// (~1500-2000cyc) old instead of ~2 - ages the drain past the L2-miss
// latency tail. Write-safety unchanged: both stages write buf (g+1)&1,
// whose last readers (tile g-1) passed the g-1->g boundary barrier.
// 512 thr = 8 waves (2 code-halves x 4 xrow-quarters); per wave 128x64 out
// via mfma_f32_32x32x16_bf16: acc[fm=4][fn=2] f32x16.
// LDS 136KB: A dbuf 2x32KB | X dbuf 2x32KB | c2 seg 8KB.
// Swizzle: rows [*][64] bf16 (128B), kbyte ^= ((row&7)<<4), applied on the
// global source (linear gload_lds dest) + on ds_read addrs (both-sides, #21).
// ---------------------------------------------------------------------------
__global__ __launch_bounds__(512, 2)
void gemm_topk_kernel(const unsigned short* __restrict__ Xb,
                      const unsigned short* __restrict__ CBb,
                      const float* __restrict__ c2g,
                      float* __restrict__ pval, int* __restrict__ pid) {
  extern __shared__ char smem[];
  float* c2s = (float*)(smem + 131072);

  const int t   = threadIdx.x;
  const int wid = t >> 6, l = t & 63;
  const int wr  = wid >> 2;          // 0..1: code half (128 rows)
  const int wc  = wid & 3;           // 0..3: xrow quarter (64 cols)
  const int l31 = l & 31, hi = l >> 5;

  const int xt    = blockIdx.x & 31;        // 32 xrow tiles
  const int seg   = blockIdx.x >> 5;        // 8 segments
  const int xbase = xt * 256;
  const int cb0   = seg * SEGC;

  // preload segment c2 into LDS (512 thr x float4 = 2048 f32)
  *(float4*)&c2s[t * 4] = *(const float4*)(c2g + cb0 + t * 4);

  // staging: issue i covers rows i*64+(t>>3); 16B col chunk (t&7), swizzled src
  const int srow = t >> 3;
  const int sswz = (((t & 7) * 16) ^ ((srow & 7) << 4)) >> 1;  // elem offset
  const int fswz = (l & 7) << 4;                                // read swizzle

  f32x16 acc[4][2];
  float tv[2][KSEL]; int ti[2][KSEL];
  #pragma unroll
  for (int fm = 0; fm < 4; ++fm)
    #pragma unroll
    for (int fn = 0; fn < 2; ++fn)
      #pragma unroll
      for (int r = 0; r < 16; ++r) acc[fm][fn][r] = 0.f;
  #pragma unroll
  for (int fn = 0; fn < 2; ++fn)
    #pragma unroll
    for (int q = 0; q < KSEL; ++q) { tv[fn][q] = -FLT_MAX; ti[fn][q] = 0; }

  auto STAGE_A = [&](int g) {   // 4 loads: codes half-tiles of K-tile g
    const int kbase = (g & 15) * 64;
    const int arow0 = cb0 + (g >> 4) * 256;
    char* As = smem + (g & 1) * 32768;
    #pragma unroll
    for (int i = 0; i < 4; ++i)
      gload_lds16(CBb + (size_t)(arow0 + i * 64 + srow) * D_DIM + kbase + sswz,
                  As + (i * 512 + t) * 16);
  };
  auto STAGE_X = [&](int g) {   // 4 loads: xrow half-tiles of K-tile g
    const int kbase = (g & 15) * 64;
    char* Xs = smem + 65536 + (g & 1) * 32768;
    #pragma unroll
    for (int i = 0; i < 4; ++i)
      gload_lds16(Xb + (size_t)(xbase + i * 64 + srow) * D_DIM + kbase + sswz,
                  Xs + (i * 512 + t) * 16);
  };

  // two named fragment sets (static indexing only - rule 20)
  short8v avE[4], bvE[2], avO[4], bvO[2];

#define READ_FRAGS(AV, BV, ABUF, XBUF, P)                                       \
  {                                                                             \
    const int kb_ = ((P) * 32 + hi * 16) ^ fswz;                                \
    _Pragma("unroll")                                                           \
    for (int fm_ = 0; fm_ < 4; ++fm_)                                           \
      AV[fm_] = *(const short8v*)((ABUF) +                                      \
                    (wr * 128 + fm_ * 32 + l31) * 128 + kb_);                   \
    _Pragma("unroll")                                                           \
    for (int fn_ = 0; fn_ < 2; ++fn_)                                           \
      BV[fn_] = *(const short8v*)((XBUF) +                                      \
                    (wc * 64 + fn_ * 32 + l31) * 128 + kb_);                    \
  }

#define MFMA8(AV, BV)                                                           \
  {                                                                             \
    __builtin_amdgcn_s_setprio(1);                                              \
    _Pragma("unroll")                                                           \
    for (int fm_ = 0; fm_ < 4; ++fm_)                                           \
      _Pragma("unroll")                                                         \
      for (int fn_ = 0; fn_ < 2; ++fn_)                                         \
        acc[fm_][fn_] = __builtin_amdgcn_mfma_f32_32x32x16_bf16(                \
            AV[fm_], BV[fn_], acc[fm_][fn_], 0, 0, 0);                          \
    __builtin_amdgcn_s_setprio(0);                                              \
    __builtin_amdgcn_sched_barrier(0);                                          \
  }

  // ---- prologue: stage tile 0, drain, pre-read ks0 frags ----
  STAGE_A(0); STAGE_X(0);
  asm volatile("s_waitcnt vmcnt(0) lgkmcnt(0)" ::: "memory");
  __builtin_amdgcn_s_barrier();
  __builtin_amdgcn_sched_barrier(0);
  READ_FRAGS(avE, bvE, (const char*)smem, (const char*)smem + 65536, 0);

  for (int g = 0; g < NKT; ++g) {
    const char* As  = smem + (g & 1) * 32768;
    const char* Xs  = smem + 65536 + (g & 1) * 32768;
    const char* Asn = smem + ((g + 1) & 1) * 32768;
    const char* Xsn = smem + 65536 + ((g + 1) & 1) * 32768;
    const bool more = (g + 1 < NKT);

    // --- p0: consume E(ks0), issue O(ks1), stage BOTH A(g+1) and X(g+1) ---
    READ_FRAGS(avO, bvO, As, Xs, 1);
    if (more) { STAGE_A(g + 1); STAGE_X(g + 1); }
    __builtin_amdgcn_s_barrier();
    MFMA8(avE, bvE);

    // --- p1: consume O(ks1), issue E(ks2) ---
    READ_FRAGS(avE, bvE, As, Xs, 2);
    __builtin_amdgcn_s_barrier();
    MFMA8(avO, bvO);

    // --- p2: consume E(ks2), issue O(ks3) ---
    READ_FRAGS(avO, bvO, As, Xs, 3);
    __builtin_amdgcn_s_barrier();
    MFMA8(avE, bvE);

    // --- p3: consume O(ks3), pre-read E(ks0 of g+1) from other buffer ---
    asm volatile("s_waitcnt vmcnt(0)" ::: "memory");  // stage g+1: ~3 phases old
    __builtin_amdgcn_s_barrier();                      // ALL waves' stages landed
    __builtin_amdgcn_sched_barrier(0);
    if (more) READ_FRAGS(avE, bvE, Asn, Xsn, 0);
    MFMA8(avO, bvO);

    if ((g & 15) == 15) {
      // -------- selection epilogue for chunk ch (registers + c2s only) -----
      const int ch = g >> 4;
      #pragma unroll
      for (int fm = 0; fm < 4; ++fm) {
        const int rloc = ch * 256 + wr * 128 + fm * 32 + hi * 4;
        const int idb  = cb0 + ch * 256 + wr * 128 + fm * 32 + hi * 4;
        #pragma unroll
        for (int q = 0; q < 4; ++q) {
          const float4 cq = *(const float4*)&c2s[rloc + q * 8];
          #pragma unroll
          for (int fn = 0; fn < 2; ++fn) {
            #pragma unroll
            for (int r = 0; r < 4; ++r) {
              const float c2v = (r == 0) ? cq.x : (r == 1) ? cq.y : (r == 2) ? cq.z : cq.w;
              const float s = 2.f * acc[fm][fn][q * 4 + r] - c2v;
              if (s > tv[fn][KSEL - 1]) {      // strict >: ids scanned ascending
                float cv = s; int ci = idb + q * 8 + r;
                #pragma unroll
                for (int q2 = 0; q2 < KSEL; ++q2) {
                  if (cv > tv[fn][q2]) {
                    const float t0 = tv[fn][q2]; tv[fn][q2] = cv; cv = t0;
                    const int   t1 = ti[fn][q2]; ti[fn][q2] = ci; ci = t1;
                  }
                }
              }
            }
          }
        }
      }
      #pragma unroll
      for (int fm = 0; fm < 4; ++fm)
        #pragma unroll
        for (int fn = 0; fn < 2; ++fn)
          #pragma unroll
          for (int r = 0; r < 16; ++r) acc[fm][fn][r] = 0.f;
    }
  }

#undef READ_FRAGS
#undef MFMA8

  // -------- merge 4 lane-lists per xrow, write per-segment top-8 --------
  asm volatile("s_waitcnt vmcnt(0) lgkmcnt(0)" ::: "memory");
  __builtin_amdgcn_s_barrier();
  float* mv = (float*)smem;            // [256 xrows][4 lists][8] = 32KB
  int*   mi = (int*)(smem + 32768);
  #pragma unroll
  for (int fn = 0; fn < 2; ++fn) {
    const int xrL = wc * 64 + fn * 32 + l31;
    const int li  = wr * 2 + hi;
    #pragma unroll
    for (int q = 0; q < KSEL; ++q) {
      mv[xrL * 32 + li * 8 + q] = tv[fn][q];
      mi[xrL * 32 + li * 8 + q] = ti[fn][q];
    }
  }
  __syncthreads();
  if (t < 256) {
    float bvv[KSEL]; int bii[KSEL];
    #pragma unroll
    for (int q = 0; q < KSEL; ++q) { bvv[q] = -FLT_MAX; bii[q] = 0x7fffffff; }
    for (int c = 0; c < 32; ++c) {
      float cv = mv[t * 32 + c]; int ci = mi[t * 32 + c];
      if (cv > bvv[KSEL - 1] || (cv == bvv[KSEL - 1] && ci < bii[KSEL - 1])) {
        #pragma unroll
        for (int q = 0; q < KSEL; ++q) {
          if (cv > bvv[q] || (cv == bvv[q] && ci < bii[q])) {
            const float t0 = bvv[q]; bvv[q] = cv; cv = t0;
            const int   t1 = bii[q]; bii[q] = ci; ci = t1;
          }
        }
      }
    }
    const size_t base = ((size_t)(xbase + t) * NSPLIT + seg) * KSEL;
    #pragma unroll
    for (int q = 0; q < KSEL; ++q) { pval[base + q] = bvv[q]; pid[base + q] = bii[q]; }
  }
}

// ---------------------------------------------------------------------------
// Kernel 2: per row: merge 64 approx candidates -> top-16, exact f32 rescore
// of those 16, final top-8 (ties: lower id), gather + average. (r11/r14/r16,
// passed; ~100us; r15's LDS-staged variant measured +210us - keep as is.)
// ---------------------------------------------------------------------------
__global__ __launch_bounds__(256)
void rescore_kernel(const float* __restrict__ X, const float* __restrict__ CB,
                    const float* __restrict__ c2g,
                    const float* __restrict__ pval, const int* __restrict__ pid,
                    float* __restrict__ out, float* __restrict__ out_ids) {
  const int row = blockIdx.x;
  const int t = threadIdx.x;
  __shared__ float xs[D_DIM];
  __shared__ int   scid[NC_RES];
  __shared__ float sv[NC_RES];
  __shared__ int   topid[KSEL];

  *(float4*)&xs[t * 4] = *(const float4*)(X + (size_t)row * D_DIM + t * 4);

  const int ncand = NSPLIT * KSEL;          // 64

  if (t < 64) {   // wave 0: merge candidates by approx score -> top-NC ids
    float v   = pval[(size_t)row * ncand + t];
    int   idv = pid [(size_t)row * ncand + t];
    for (int it = 0; it < NC_RES; ++it) {
      float bv = v; int bid = idv;
      #pragma unroll
      for (int off = 32; off >= 1; off >>= 1) {
        float ov = __shfl_xor(bv, off, 64);
        int   oi = __shfl_xor(bid, off, 64);
        if (ov > bv || (ov == bv && oi < bid)) { bv = ov; bid = oi; }
      }
      if (t == 0) scid[it] = bid;
      if (idv == bid) v = -FLT_MAX;   // remove winner (ids unique)
    }
  }
  __syncthreads();

  const int w = t >> 6, ln = t & 63;
  for (int c = w; c < NC_RES; c += 4) {
    const int id = scid[c];
    const float* cr = CB + (size_t)id * D_DIM;
    float s = 0.f;
    #pragma unroll
    for (int i = 0; i < 4; ++i) {
      const float4 cv = *(const float4*)(cr + ln * 4 + i * 256);
      const float4 xv = *(const float4*)&xs[ln * 4 + i * 256];
      s += cv.x * xv.x + cv.y * xv.y + cv.z * xv.z + cv.w * xv.w;
    }
    #pragma unroll
    for (int off = 32; off >= 1; off >>= 1) s += __shfl_xor(s, off, 64);
    if (ln == 0) sv[c] = 2.f * s - c2g[id];
  }
  __syncthreads();

  if (t == 0) {
    float bv[KSEL]; int bi[KSEL];
    #pragma unroll
    for (int q = 0; q < KSEL; ++q) { bv[q] = -FLT_MAX; bi[q] = 0x7fffffff; }
    for (int c = 0; c < NC_RES; ++c) {
      float cv = sv[c]; int ci = scid[c];
      #pragma unroll
      for (int q = 0; q < KSEL; ++q) {
        if (cv > bv[q] || (cv == bv[q] && ci < bi[q])) {
          const float t0 = bv[q]; bv[q] = cv; cv = t0;
          const int   t1 = bi[q]; bi[q] = ci; ci = t1;
        }
      }
    }
    #pragma unroll
    for (int q = 0; q < KSEL; ++q) {
      topid[q] = bi[q];
      out_ids[(size_t)row * KSEL + q] = (float)bi[q];
    }
  }
  __syncthreads();

  float4 a = {0.f, 0.f, 0.f, 0.f};
  #pragma unroll
  for (int q = 0; q < KSEL; ++q) {
    const float4 cv = *(const float4*)(CB + (size_t)topid[q] * D_DIM + t * 4);
    a.x += cv.x; a.y += cv.y; a.z += cv.z; a.w += cv.w;
  }
  a.x *= 0.125f; a.y *= 0.125f; a.z *= 0.125f; a.w *= 0.125f;
  *(float4*)(out + (size_t)row * D_DIM + t * 4) = a;
}

// ---------------------------------------------------------------------------
extern "C" void kernel_launch(void* const* d_in, const int* in_sizes, int n_in,
                              void* d_out, int out_size, void* d_ws, size_t ws_size,
                              hipStream_t stream) {
  const float* X  = (const float*)d_in[0];
  const float* CB = (const float*)d_in[1];
  // d_in[2] = kcodes, fixed at 8 (compiled in)

  float* out     = (float*)d_out;
  float* out_ids = out + XN;

  const size_t XbB  = XN * 2;        // 16 MB
  const size_t CBbB = CBN * 2;       // 32 MB
  const size_t c2B  = C_TOTAL * 4;   // 64 KB
  const size_t pvB  = (size_t)R_TOTAL * NSPLIT * KSEL * 4;  // 2 MB

  char* p = (char*)d_ws;
  unsigned short* Xb;
  unsigned short* CBb;
  if (ws_size >= XbB + CBbB + c2B + 2 * pvB) {
    Xb  = (unsigned short*)p; p += XbB;
    CBb = (unsigned short*)p; p += CBbB;
  } else {
    // CB bf16 lives in d_out's outputs region (overwritten at the very end)
    CBb = (unsigned short*)d_out;
    Xb  = (unsigned short*)p; p += XbB;
  }
  float* c2   = (float*)p; p += c2B;
  float* pval = (float*)p; p += pvB;
  int*   pid  = (int*)p;

  hipLaunchKernelGGL(cvt_c2_kernel, dim3((R_TOTAL + C_TOTAL) / 4), dim3(256), 0, stream,
                     X, CB, Xb, CBb, c2);
  hipLaunchKernelGGL(gemm_topk_kernel, dim3(32 * NSPLIT), dim3(512), 136 * 1024, stream,
                     Xb, CBb, c2, pval, pid);
  hipLaunchKernelGGL(rescore_kernel, dim3(R_TOTAL), dim3(256), 0, stream,
                     X, CB, c2, pval, pid, out, out_ids);
}